// Round 8
// baseline (224.632 us; speedup 1.0000x reference)
//
#include <hip/hip_runtime.h>

// GNB dispersion — Round 8: lean scatter (TILE=2048, regs across barrier, 19.5KB LDS,
// 8 blocks/CU) + pid-classed energy gather (1B sender gather + LDS param table).
//   init (zero + isCN + PT table) -> scatter -> params(pid) -> energy(+ovf tail) -> reduce
// Record: uint2{ x = s | (r&1023)<<17, y = len bits }; bucket id = r>>10.
// Assumes n_nodes <= 131072 (17-bit ids), NB2 <= 128.

#define B2SHIFT 10
#define B2SIZE  1024
#define TILE    2048
#define SBLK    256
#define ESLICES 16
#define MAXB    128
#define OVB     8

__device__ __constant__ float2 GNB_RC6[87] = {
    {0.f, 0.f},
    {3.6516f, 95.99f},   {2.1843f, 40.67f},   {1.2711f, 70.21f},
    {3.3497f, 114.51f},  {2.7079f, 152.36f},  {1.8219f, 184.28f},
    {2.4667f, 482.54f},  {2.365f, 405.57f},   {1.5062f, 218.45f},
    {1.8233f, 174.81f},  {1.3974f, 181.7f},   {3.3515f, 263.02f},
    {3.0102f, 228.1f},   {3.1629f, 359.43f},  {3.2554f, 3222.12f},
    {2.9539f, 2144.49f}, {3.0368f, 2072.46f}, {2.6598f, 1357.42f},
    {4.0877f, 1406.65f}, {4.1275f, 1058.36f}, {9.7282f, 11498.73f},
    {8.5322f, 3361.33f}, {7.2344f, 2095.91f}, {5.3605f, 1049.31f},
    {3.718f, 966.27f},   {3.6408f, 1571.36f}, {3.4961f, 1183.59f},
    {3.5108f, 787.76f},  {3.0537f, 563.93f},  {3.0261f, 592.91f},
    {3.1735f, 430.82f},  {3.1773f, 812.57f},  {3.8357f, 4533.53f},
    {3.1109f, 3440.92f}, {3.2122f, 3859.82f}, {2.8263f, 2729.6f},
    {2.412f, 1864.19f},  {1.894f, 1175.73f},  {11.2061f, 32141.18f},
    {6.821f, 27655.14f}, {7.2367f, 2864.2f},  {3.901f, 3563.45f},
    {4.0857f, 3266.43f}, {4.045f, 3967.23f},  {3.4813f, 2233.82f},
    {3.0487f, 1393.49f}, {2.7795f, 1315.09f}, {2.8673f, 1311.47f},
    {3.3339f, 1460.56f}, {3.0086f, 1662.99f}, {3.9919f, 8089.97f},
    {3.4209f, 6887.05f}, {3.5649f, 8799.32f}, {3.0288f, 6136.5f},
    {2.262f, 3757.31f},  {1.3837f, 2561.18f}, {12.171f, 66580.83f},
    {0.f,0.f},{0.f,0.f},{0.f,0.f},{0.f,0.f},{0.f,0.f},{0.f,0.f},{0.f,0.f},
    {0.f,0.f},{0.f,0.f},{0.f,0.f},{0.f,0.f},{0.f,0.f},{0.f,0.f},{0.f,0.f},
    {6.0791f, 27593.76f}, {5.7661f, 15364.65f}, {3.6366f, 2734.5f},
    {4.241f, 4801.82f},   {4.1348f, 5685.94f},  {3.4213f, 2786.0f},
    {3.2486f, 2699.79f},  {2.9588f, 2282.6f},   {2.9381f, 2476.79f},
    {2.7711f, 2988.7f},   {2.5816f, 2506.63f},  {3.785f, 8916.84f},
    {3.5381f, 8694.22f},  {3.6985f, 11821.61f}, {3.0551f, 8410.64f},
};

// Zero scratch, build isCN bitmask, build 91-entry param table
// PT[id] = {sqrt(C6), R^(1/4)}; ids 87/88 = C sp2/sp3, 89/90 = N cn<=2/cn>=3.
__global__ void gnb_init(const int* __restrict__ Z, unsigned* __restrict__ isCN,
                         float2* __restrict__ PT, int nw, int n_nodes,
                         int* __restrict__ zp, int zwords) {
    int stride = gridDim.x * blockDim.x;
    int t0 = blockIdx.x * blockDim.x + threadIdx.x;
    for (int i = t0; i < zwords; i += stride) zp[i] = 0;
    for (int w = t0; w < nw; w += stride) {
        unsigned m = 0;
        int base = w << 5;
        int lim = n_nodes - base; if (lim > 32) lim = 32;
        for (int k = 0; k < lim; ++k) {
            int z = Z[base + k];
            if (z == 6 || z == 7) m |= (1u << k);
        }
        isCN[w] = m;
    }
    if (t0 < 91) {
        float R, C6;
        if      (t0 < 87)  { float2 rc = GNB_RC6[t0]; R = rc.x; C6 = rc.y; }
        else if (t0 == 87) { R = 2.2348f; C6 = 429.69f; }   // C sp2
        else if (t0 == 88) { R = 1.8219f; C6 = 184.28f; }   // C sp3
        else if (t0 == 89) { R = 2.6454f; C6 = 720.18f; }   // N cn<=2
        else               { R = 2.4667f; C6 = 482.54f; }   // N cn>=3
        PT[t0] = make_float2(sqrtf(C6), sqrtf(sqrtf(R)));
    }
}

// Tile scatter, 2048 edges / 256 threads, (r,len) held in regs across barriers.
// LDS 19.5KB -> 8 blocks/CU. Degree fused (isCN-filtered). r>=10 edges dropped.
__global__ void __launch_bounds__(SBLK, 8)
gnb_scatter(const int* __restrict__ send, const int* __restrict__ recv,
            const float* __restrict__ len, const unsigned* __restrict__ isCN,
            int* __restrict__ cn,
            uint2* __restrict__ buckets, unsigned* __restrict__ cursor,
            uint4* __restrict__ ovrec, unsigned* __restrict__ ocur,
            int n_edges, int cap, unsigned ocap, int NB2) {
    __shared__ unsigned cnt[MAXB + 1];   // counts -> startp -> pass2 cursor
    __shared__ unsigned gbase[MAXB];     // cursor base - startp
    __shared__ uint2 srec[TILE];         // 16 KB bucket-sorted records
    __shared__ unsigned char bmap[TILE]; // 2 KB slot -> bucket
    const int tid = threadIdx.x;
    const int e0  = blockIdx.x * TILE;

    for (int b = tid; b < MAXB + 1; b += SBLK) cnt[b] = 0;
    __syncthreads();

    unsigned rv[8];   // receiver; 0xFFFFFFFF = invalid tail slot
    float    lv[8];

    // pass 1: fill regs, histogram kept (len<10), degree for all edges
    #pragma unroll
    for (int k = 0; k < 2; ++k) {
        int base = e0 + (k * SBLK + tid) * 4;
        if (base + 3 < n_edges) {
            int4   rr = *(const int4*)(recv + base);
            float4 ll = *(const float4*)(len + base);
            rv[k*4+0] = (unsigned)rr.x; lv[k*4+0] = ll.x;
            rv[k*4+1] = (unsigned)rr.y; lv[k*4+1] = ll.y;
            rv[k*4+2] = (unsigned)rr.z; lv[k*4+2] = ll.z;
            rv[k*4+3] = (unsigned)rr.w; lv[k*4+3] = ll.w;
        } else {
            for (int j = 0; j < 4; ++j) {
                int e = base + j;
                if (e < n_edges) { rv[k*4+j] = (unsigned)recv[e]; lv[k*4+j] = len[e]; }
                else             { rv[k*4+j] = 0xFFFFFFFFu;       lv[k*4+j] = 1e30f; }
            }
        }
    }
    #pragma unroll
    for (int i = 0; i < 8; ++i) {
        unsigned r = rv[i];
        if (r == 0xFFFFFFFFu) continue;
        if ((isCN[r >> 5] >> (r & 31)) & 1u) atomicAdd(&cn[r], 1);
        if (lv[i] < 10.0f) atomicAdd(&cnt[r >> B2SHIFT], 1u);
    }
    __syncthreads();

    // cursor bump (raw bases) — cnt still holds counts
    if (tid < NB2) gbase[tid] = atomicAdd(&cursor[tid], cnt[tid]);
    __syncthreads();

    // in-place exclusive scan + gbase adjust (98 iters, tid0)
    if (tid == 0) {
        unsigned acc = 0;
        for (int b = 0; b < NB2; ++b) {
            unsigned c = cnt[b];
            cnt[b] = acc;          // startp (becomes pass-2 cursor)
            gbase[b] -= acc;       // g = gbase[b] + slot
            acc += c;
        }
        cnt[NB2] = acc;            // total kept records
    }
    __syncthreads();

    // pass 2: load send, place records bucket-sorted in LDS
    #pragma unroll
    for (int k = 0; k < 2; ++k) {
        int base = e0 + (k * SBLK + tid) * 4;
        unsigned sv[4];
        if (base + 3 < n_edges) {
            int4 s4 = *(const int4*)(send + base);
            sv[0]=(unsigned)s4.x; sv[1]=(unsigned)s4.y; sv[2]=(unsigned)s4.z; sv[3]=(unsigned)s4.w;
        } else {
            for (int j = 0; j < 4; ++j)
                sv[j] = (base + j < n_edges) ? (unsigned)send[base + j] : 0u;
        }
        #pragma unroll
        for (int j = 0; j < 4; ++j) {
            int i = k * 4 + j;
            if (rv[i] == 0xFFFFFFFFu || lv[i] >= 10.0f) continue;
            unsigned r = rv[i];
            unsigned b = r >> B2SHIFT;
            unsigned slot = atomicAdd(&cnt[b], 1u);
            srec[slot] = make_uint2(sv[j] | ((r & (B2SIZE - 1)) << 17),
                                    __float_as_uint(lv[i]));
            bmap[slot] = (unsigned char)b;
        }
    }
    __syncthreads();

    // phase C: coalesced copy of bucket runs
    unsigned total = cnt[NB2];
    for (unsigned i = tid; i < total; i += SBLK) {
        unsigned b = bmap[i];
        unsigned g = gbase[b] + i;
        uint2 rec = srec[i];
        if (g < (unsigned)cap) {
            buckets[(size_t)b * cap + g] = rec;
        } else {
            unsigned o = atomicAdd(ocur, 1u);
            unsigned r = (b << B2SHIFT) | ((rec.x >> 17) & (B2SIZE - 1));
            if (o < ocap) ovrec[o] = make_uint4(r, rec.x & 0x1FFFFu, rec.y, 0u);
        }
    }
}

// Emit cn-resolved parameter class id per node (1 byte).
__global__ void gnb_params(const int* __restrict__ Z, const int* __restrict__ cn,
                           unsigned char* __restrict__ pid, int n_nodes) {
    int i = blockIdx.x * blockDim.x + threadIdx.x;
    if (i >= n_nodes) return;
    int z = Z[i];
    int id = z;
    if (z == 6)      id = (cn[i] <= 3) ? 87 : 88;
    else if (z == 7) id = (cn[i] <= 2) ? 89 : 90;
    pid[i] = (unsigned char)id;
}

__device__ __forceinline__ float gnb_energy_eval(float2 ps, float2 pr, float rlen) {
    float env;
    if (rlen < 8.0f) {
        env = 1.0f;
    } else {
        float x = (rlen - 8.0f) * 0.5f;          // records guarantee x < 1
        float x2 = x * x;
        float x6 = x2 * x2 * x2;
        env = 1.0f - 28.0f * x6 + 48.0f * x6 * x - 21.0f * x6 * x2;
    }
    float sR  = ps.y * pr.y;                     // sqrt(R_ij)
    float C6  = ps.x * pr.x;                     // sqrt(C6_s*C6_r)
    float Rij = sR * sR;
    float R3  = Rij * Rij * Rij;
    float R6  = R3 * R3;
    float r0  = 0.4f * sR + 4.0f;
    float t   = r0 / rlen;
    float t2 = t * t, t4 = t2 * t2, t8 = t4 * t4;
    float t14 = t8 * t4 * t2;
    float fd = 1.0f / (1.0f + 6.0f * t14);
    float rl2 = rlen * rlen;
    float r6 = rl2 * rl2 * rl2;
    return -0.5f * C6 / (R6 + r6) * fd * env;
}

// Main blocks: per (bin,slice) accumulate records into LDS bin; sender params via
// 1B pid gather + LDS table. Tail OVB blocks: process overflow queue.
__global__ void __launch_bounds__(256)
gnb_energy(const uint2* __restrict__ buckets, const unsigned* __restrict__ cursor,
           const float2* __restrict__ PT, const unsigned char* __restrict__ pid,
           float* __restrict__ rep, float* __restrict__ ovf,
           const uint4* __restrict__ ovrec, const unsigned* __restrict__ ocur,
           unsigned ocap, int cap, int n_nodes, int nmain) {
    __shared__ float  acc[2][B2SIZE + 8];
    __shared__ float2 p2loc[B2SIZE];
    __shared__ float2 ptab[96];
    const int tid = threadIdx.x;
    const int bid = blockIdx.x;
    const int b   = bid / ESLICES;        // valid only for main blocks
    const int rr  = (tid >> 6) & 1;

    if (tid < 91) ptab[tid] = PT[tid];
    if (bid < nmain) {
        for (int i = tid; i < 2 * (B2SIZE + 8); i += 256) acc[0][i] = 0.0f;
        for (int i = tid; i < B2SIZE; i += 256) {
            int node = (b << B2SHIFT) + i;
            p2loc[i] = (node < n_nodes) ? PT[pid[node]] : make_float2(0.f, 0.f);
        }
    }
    __syncthreads();

    if (bid >= nmain) {                   // overflow tail blocks
        unsigned n = *ocur; if (n > ocap) n = ocap;
        unsigned t0 = (unsigned)(bid - nmain) * 256 + tid;
        for (unsigned i = t0; i < n; i += OVB * 256) {
            uint4 rec = ovrec[i];
            float rlen = __uint_as_float(rec.z);
            if (rlen >= 10.0f) continue;
            float e = gnb_energy_eval(ptab[pid[rec.y]], ptab[pid[rec.x]], rlen);
            atomicAdd(&ovf[rec.x], e);
        }
        return;
    }

    const int sl = bid % ESLICES;
    unsigned count = cursor[b];
    if (count > (unsigned)cap) count = (unsigned)cap;
    unsigned seg = (((count + ESLICES - 1) / ESLICES) + 1) & ~1u;   // even
    unsigned st  = (unsigned)sl * seg;
    unsigned en  = st + seg; if (en > count) en = count;

    const uint2* src = buckets + (size_t)b * cap;
    for (unsigned i = st + 2 * tid; i < en; i += 512) {
        if (i + 1 < en) {
            uint4 q = *(const uint4*)(src + i);       // two records, 16B aligned
            {
                unsigned s = q.x & 0x1FFFFu, rl = (q.x >> 17) & (B2SIZE - 1);
                float e = gnb_energy_eval(ptab[pid[s]], p2loc[rl], __uint_as_float(q.y));
                atomicAdd(&acc[rr][rl], e);
            }
            {
                unsigned s = q.z & 0x1FFFFu, rl = (q.z >> 17) & (B2SIZE - 1);
                float e = gnb_energy_eval(ptab[pid[s]], p2loc[rl], __uint_as_float(q.w));
                atomicAdd(&acc[rr][rl], e);
            }
        } else {
            uint2 rec = src[i];
            unsigned s = rec.x & 0x1FFFFu, rl = (rec.x >> 17) & (B2SIZE - 1);
            float e = gnb_energy_eval(ptab[pid[s]], p2loc[rl], __uint_as_float(rec.y));
            atomicAdd(&acc[rr][rl], e);
        }
    }
    __syncthreads();

    float* dst = rep + (size_t)bid * B2SIZE;
    for (int i = tid; i < B2SIZE; i += 256) dst[i] = acc[0][i] + acc[1][i];
}

__global__ void gnb_reduce(const float* __restrict__ rep, const float* __restrict__ ovf,
                           float* __restrict__ out, int n_nodes) {
    int i = blockIdx.x * blockDim.x + threadIdx.x;
    if (i >= n_nodes) return;
    int b = i >> B2SHIFT;
    int j = i & (B2SIZE - 1);
    const float* src = rep + ((size_t)b * ESLICES) * B2SIZE + j;
    float sum = ovf[i];
    #pragma unroll
    for (int s = 0; s < ESLICES; ++s) sum += src[(size_t)s * B2SIZE];
    out[i] = sum;
}

extern "C" void kernel_launch(void* const* d_in, const int* in_sizes, int n_in,
                              void* d_out, int out_size, void* d_ws, size_t ws_size,
                              hipStream_t stream) {
    const int*   Z    = (const int*)d_in[0];
    const int*   eidx = (const int*)d_in[1];
    const float* len  = (const float*)d_in[2];
    float*       out  = (float*)d_out;

    const int n_nodes = in_sizes[0];
    const int n_edges = in_sizes[2];
    const int* send = eidx;
    const int* recv = eidx + n_edges;

    const int NB2 = (n_nodes + B2SIZE - 1) >> B2SHIFT;   // 98 for n=100000
    const size_t nw  = (size_t)(n_nodes + 31) >> 5;
    const size_t nwp = (nw + 3) & ~3ull;
    const size_t npidw = (((size_t)n_nodes + 3) / 4 + 3) & ~3ull;

    // ws layout in 32-bit words
    size_t o_cursor = 0;                        // 128
    size_t o_ocur   = 128;                      // 8
    size_t o_cn     = 136;                      // n
    size_t o_ovf    = o_cn + n_nodes;           // n
    size_t o_PT     = o_ovf + n_nodes;          // 192 (91 float2, padded)
    size_t o_isCN   = o_PT + 192;               // nwp
    size_t o_pid    = o_isCN + nwp;             // npidw
    size_t o_rep    = (o_pid + npidw + 3) & ~3ull;
    size_t rep_w    = (size_t)NB2 * ESLICES * B2SIZE;
    size_t o_tail   = (o_rep + rep_w + 3) & ~3ull;

    char* ws = (char*)d_ws;
    unsigned*      cursor = (unsigned*)(ws + o_cursor * 4);
    unsigned*      ocur   = (unsigned*)(ws + o_ocur * 4);
    int*           cn     = (int*)(ws + o_cn * 4);
    float*         ovf    = (float*)(ws + o_ovf * 4);
    float2*        PT     = (float2*)(ws + o_PT * 4);
    unsigned*      isCN   = (unsigned*)(ws + o_isCN * 4);
    unsigned char* pid    = (unsigned char*)(ws + o_pid * 4);
    float*         rep    = (float*)(ws + o_rep * 4);

    size_t total_words = ws_size / 4;
    size_t avail = total_words > o_tail ? total_words - o_tail : 0;
    size_t ovw = avail / 32;                      // ~3% to overflow queue
    unsigned ocap = (unsigned)(ovw / 4);
    long cap = (long)((avail - ovw) / (2 * (size_t)NB2));
    if (cap > n_edges) cap = (long)n_edges;
    if (cap < 0) cap = 0;
    cap &= ~1L;                                   // even -> 16B-aligned pairs
    uint4* ovrec   = (uint4*)(ws + o_tail * 4);
    uint2* buckets = (uint2*)(ws + (o_tail + (size_t)ocap * 4) * 4);

    const int B = 256;
    int node_blocks = (n_nodes + B - 1) / B;
    int scat_blocks = (n_edges + TILE - 1) / TILE;
    int zero_words  = (int)o_PT;                  // cursor+ocur+cn+ovf
    int nmain = NB2 * ESLICES;

    gnb_init<<<1024, B, 0, stream>>>(Z, isCN, PT, (int)nw, n_nodes, (int*)ws, zero_words);
    gnb_scatter<<<scat_blocks, SBLK, 0, stream>>>(send, recv, len, isCN, cn, buckets,
                                                  cursor, ovrec, ocur, n_edges,
                                                  (int)cap, ocap, NB2);
    gnb_params<<<node_blocks, B, 0, stream>>>(Z, cn, pid, n_nodes);
    gnb_energy<<<nmain + OVB, B, 0, stream>>>(buckets, cursor, PT, pid, rep, ovf,
                                              ovrec, ocur, ocap, (int)cap, n_nodes, nmain);
    gnb_reduce<<<node_blocks, B, 0, stream>>>(rep, ovf, out, n_nodes);
}